// Round 1
// baseline (8216.766 us; speedup 1.0000x reference)
//
#include <hip/hip_runtime.h>

// INRF: out[b,i,j,c] = first[b,i,j,c] - second[b,i,j,c]
//   first[b,i,j,c]  = sum_pq M2[ij,pq] * inp[b,pq,c]
//   shifted[b,p,q,i,j,f] = sum_{dh,dw,c} inp[b,p+dh-1,q+dw-1,c] * G[i,j,dh,dw,c,f]
//   second[b,i,j,c] = sum_pq W2[ij,pq] * relu(inp[b,pq,c] - shifted[b,p,q,i,j,c])
// Shapes: B=4, H=W=32, C=F=16, KH=KW=3. One workgroup per (i,j).

constexpr int HW  = 32;
constexpr int NC  = 16;
constexpr int NB  = 4;
constexpr int NPQ = HW * HW;   // 1024

__global__ __launch_bounds__(256) void inrf_main(
    const float* __restrict__ inp,   // (4,32,32,16)
    const float* __restrict__ M,     // (32,32,1,32,32,1) -> rows of 1024
    const float* __restrict__ Wp,    // same layout as M
    const float* __restrict__ G,     // (32,32,3,3,16,16) -> blocks of 2304
    float* __restrict__ out)         // (4,32,32,16)
{
    const int ij = blockIdx.x;       // 0..1023
    const int t  = threadIdx.x;      // 0..255

    __shared__ __align__(16) float G_l[2304];
    __shared__ float W_l[1024];
    __shared__ float M_l[1024];
    __shared__ float red[256];
    __shared__ float sec_l[64];

    {
        const float* Gs = G  + ij * 2304;
        for (int i = t; i < 2304; i += 256) G_l[i] = Gs[i];
        const float* Ws = Wp + ij * 1024;
        const float* Ms = M  + ij * 1024;
        for (int i = t; i < 1024; i += 256) { W_l[i] = Ws[i]; M_l[i] = Ms[i]; }
    }
    __syncthreads();

    const int b    = t >> 6;         // one wave per batch element
    const int lane = t & 63;
    const float* inb = inp + b * (NPQ * NC);

    float acc[16];
#pragma unroll
    for (int f = 0; f < 16; ++f) acc[f] = 0.f;

    // Each lane handles 16 pq positions, 2 in flight for G reuse.
    for (int k = 0; k < 8; ++k) {
        const int pq0 = lane + 128 * k;
        const int pq1 = pq0 + 64;
        const int p0 = pq0 >> 5, q0 = pq0 & 31;
        const int p1 = pq1 >> 5, q1 = pq1 & 31;

        float s0[16], s1[16];
#pragma unroll
        for (int f = 0; f < 16; ++f) { s0[f] = 0.f; s1[f] = 0.f; }

#pragma unroll
        for (int dh = 0; dh < 3; ++dh) {
#pragma unroll
            for (int dw = 0; dw < 3; ++dw) {
                const int pp0 = p0 + dh - 1, qq0 = q0 + dw - 1;
                const int pp1 = p1 + dh - 1, qq1 = q1 + dw - 1;
                const bool v0 = ((unsigned)pp0 < 32u) && ((unsigned)qq0 < 32u);
                const bool v1 = ((unsigned)pp1 < 32u) && ((unsigned)qq1 < 32u);
                const float m0 = v0 ? 1.f : 0.f;
                const float m1 = v1 ? 1.f : 0.f;
                const float4* x0p = (const float4*)(inb + (v0 ? (pp0*32 + qq0)*16 : 0));
                const float4* x1p = (const float4*)(inb + (v1 ? (pp1*32 + qq1)*16 : 0));

                float x0[16], x1[16];
#pragma unroll
                for (int g4 = 0; g4 < 4; ++g4) {
                    float4 a = x0p[g4], c4 = x1p[g4];
                    x0[g4*4+0] = m0*a.x;  x0[g4*4+1] = m0*a.y;
                    x0[g4*4+2] = m0*a.z;  x0[g4*4+3] = m0*a.w;
                    x1[g4*4+0] = m1*c4.x; x1[g4*4+1] = m1*c4.y;
                    x1[g4*4+2] = m1*c4.z; x1[g4*4+3] = m1*c4.w;
                }

                const float* gl = &G_l[(dh*3 + dw) * 256];
#pragma unroll
                for (int c = 0; c < 16; ++c) {
                    const float xc0 = x0[c], xc1 = x1[c];
                    const float4* gp = (const float4*)(gl + c*16);
#pragma unroll
                    for (int g4 = 0; g4 < 4; ++g4) {
                        float4 g = gp[g4];
                        s0[g4*4+0] += xc0*g.x; s0[g4*4+1] += xc0*g.y;
                        s0[g4*4+2] += xc0*g.z; s0[g4*4+3] += xc0*g.w;
                        s1[g4*4+0] += xc1*g.x; s1[g4*4+1] += xc1*g.y;
                        s1[g4*4+2] += xc1*g.z; s1[g4*4+3] += xc1*g.w;
                    }
                }
            }
        }

        const float w0 = W_l[pq0], w1 = W_l[pq1];
        const float4* cx0 = (const float4*)(inb + pq0*16);
        const float4* cx1 = (const float4*)(inb + pq1*16);
#pragma unroll
        for (int g4 = 0; g4 < 4; ++g4) {
            float4 a = cx0[g4], c4 = cx1[g4];
            const float xa[4] = {a.x, a.y, a.z, a.w};
            const float xb[4] = {c4.x, c4.y, c4.z, c4.w};
#pragma unroll
            for (int u = 0; u < 4; ++u) {
                const int f = g4*4 + u;
                acc[f] += w0 * fmaxf(xa[u] - s0[f], 0.f)
                        + w1 * fmaxf(xb[u] - s1[f], 0.f);
            }
        }
    }

    // second[b,c]: reduce acc over the wave's 64 lanes (one wave per b)
#pragma unroll
    for (int f = 0; f < 16; ++f) {
        float v = acc[f];
        for (int off = 32; off > 0; off >>= 1) v += __shfl_down(v, off, 64);
        if (lane == 0) sec_l[b*16 + f] = v;
    }

    // first: thread t covers (b,c)=bc over a 256-long pq chunk
    const int bc    = t & 63;
    const int chunk = t >> 6;
    const int fb = bc >> 4, fc = bc & 15;
    const float* src = inp + fb * (NPQ * NC) + fc;
    const int base = chunk * 256;
    float fs0 = 0.f, fs1 = 0.f, fs2 = 0.f, fs3 = 0.f;
    for (int r = 0; r < 256; r += 4) {
        fs0 += M_l[base+r+0] * src[(base+r+0)*16];
        fs1 += M_l[base+r+1] * src[(base+r+1)*16];
        fs2 += M_l[base+r+2] * src[(base+r+2)*16];
        fs3 += M_l[base+r+3] * src[(base+r+3)*16];
    }
    red[t] = (fs0 + fs1) + (fs2 + fs3);
    __syncthreads();

    if (t < 64) {
        const float first = red[t] + red[t+64] + red[t+128] + red[t+192];
        const int ob = t >> 4, oc = t & 15;
        out[ob * (NPQ * NC) + ij * 16 + oc] = first - sec_l[t];  // L = 1
    }
}

extern "C" void kernel_launch(void* const* d_in, const int* in_sizes, int n_in,
                              void* d_out, int out_size, void* d_ws, size_t ws_size,
                              hipStream_t stream) {
    const float* inp = (const float*)d_in[0];   // 65536
    const float* M   = (const float*)d_in[1];   // 1048576
    const float* Wp  = (const float*)d_in[2];   // 1048576
    const float* G   = (const float*)d_in[3];   // 2359296
    float* out = (float*)d_out;                 // 65536

    inrf_main<<<dim3(1024), dim3(256), 0, stream>>>(inp, M, Wp, G, out);
}

// Round 2
// 102.988 us; speedup vs baseline: 79.7834x; 79.7834x over previous
//
#include <hip/hip_runtime.h>

// INRF fused:  out[b,ij,c] = sum_pq [ M2[ij,pq]*x[b,pq,c] - W2[ij,pq]*relu(x[b,pq,c] - S[b,pq,ij,c]) ]
//   S[b,pq,ij,f] = sum_{k=(dh,dw,c)} patch(x)[b,pq,k] * G[ij,k,f]   (3x3 SAME conv, K=144)
// Strategy: phase1 im2col -> bf16 A (4096 x 160, frag-swizzled) in d_ws; main kernel
// does per-block (4 ij) MFMA GEMM + fused epilogue. B=4,H=W=32,C=F=16.

typedef __attribute__((ext_vector_type(8))) short bf16x8;
typedef __attribute__((ext_vector_type(4))) float f32x4;

__device__ inline unsigned short f2bf(float x) {
    unsigned u = __float_as_uint(x);
    u += 0x7FFFu + ((u >> 16) & 1u);          // round-to-nearest-even
    return (unsigned short)(u >> 16);
}
__device__ inline unsigned pack2(float a, float b) {
    return (unsigned)f2bf(a) | ((unsigned)f2bf(b) << 16);
}

// ---------------- Phase 1: build A in MFMA-fragment-swizzled bf16 layout ----------------
// Logical A[row=(b,pq)][k=(dh*3+dw)*16+c], K padded 144->160 with zeros.
// Storage: uint4 index = (tile*5 + kk)*64 + quad*16 + m   (tile=row>>4, m=row&15,
// kk=k/32, quad=(k%32)/8; one uint4 = 8 bf16 = j 0..7 of one quad-row).
// Main-loop load for (tile,kk) is then Aw[(tile*5+kk)*64 + lane] — fully coalesced.
__global__ __launch_bounds__(256) void build_A(const float* __restrict__ inp,
                                               uint4* __restrict__ A) {
    const int row = blockIdx.x * 256 + threadIdx.x;   // 0..4095
    const int b = row >> 10, pq = row & 1023;
    const int p = pq >> 5, q = pq & 31;
    const int tile = row >> 4, m = row & 15;
    const float* inb = inp + b * 16384;

#pragma unroll
    for (int tap = 0; tap < 9; ++tap) {
        const int dh = tap / 3, dw = tap % 3;
        const int pp = p + dh - 1, qq = q + dw - 1;
        const bool v = ((unsigned)pp < 32u) && ((unsigned)qq < 32u);
        uint4 lo = {0, 0, 0, 0}, hi = {0, 0, 0, 0};
        if (v) {
            const float4* s = (const float4*)(inb + (pp * 32 + qq) * 16);
            float4 f0 = s[0], f1 = s[1], f2 = s[2], f3 = s[3];
            lo.x = pack2(f0.x, f0.y); lo.y = pack2(f0.z, f0.w);
            lo.z = pack2(f1.x, f1.y); lo.w = pack2(f1.z, f1.w);
            hi.x = pack2(f2.x, f2.y); hi.y = pack2(f2.z, f2.w);
            hi.z = pack2(f3.x, f3.y); hi.w = pack2(f3.z, f3.w);
        }
        const int kk = tap >> 1, qa = (tap & 1) * 2;
        const int base = (tile * 5 + kk) * 64 + qa * 16 + m;
        A[base] = lo;
        A[base + 16] = hi;
    }
    // zero-pad k = 144..159 (kk=4, quads 2,3)
    const uint4 z = {0, 0, 0, 0};
    const int base = (tile * 5 + 4) * 64 + 2 * 16 + m;
    A[base] = z;
    A[base + 16] = z;
}

// ---------------- Main kernel: 256 blocks x 512 threads, 4 ij per block ----------------
__global__ __launch_bounds__(512, 2) void inrf_main(
    const float* __restrict__ inp,   // (4,1024,16)
    const float* __restrict__ M,     // rows of 1024 per ij
    const float* __restrict__ Wp,    // rows of 1024 per ij
    const float* __restrict__ G,     // 2304 per ij
    const uint4* __restrict__ Aw,    // swizzled bf16 patches
    float* __restrict__ out)         // (4,1024,16)
{
    const int bid = blockIdx.x;      // ij block: handles ij = bid*4 .. bid*4+3
    const int t = threadIdx.x;

    __shared__ __align__(16) float W2l[4096];
    __shared__ __align__(16) float M2l[4096];
    __shared__ __align__(16) float G_l[9216];
    __shared__ float red[8][64];

    {
        const float* Wg = Wp + bid * 4096;
        const float* Mg = M  + bid * 4096;
        for (int i = t; i < 4096; i += 512) { W2l[i] = Wg[i]; M2l[i] = Mg[i]; }
        const float* Gg = G + bid * 9216;
        for (int i = t; i < 9216; i += 512) G_l[i] = Gg[i];
    }
    __syncthreads();

    const int l = t & 63, w = t >> 6;      // 8 waves
    const int quad = l >> 4, col = l & 15;
    const int b = w >> 1;                  // 2 waves per batch element

    // B fragments: lane holds G[k = kk*32 + quad*8 + j][f = col], bf16
    bf16x8 Bf[4][5];
#pragma unroll
    for (int ij = 0; ij < 4; ++ij) {
#pragma unroll
        for (int kk = 0; kk < 5; ++kk) {
            bf16x8 f;
#pragma unroll
            for (int j = 0; j < 8; ++j) {
                const int k = kk * 32 + quad * 8 + j;
                const float v = (k < 144) ? G_l[ij * 2304 + k * 16 + col] : 0.f;
                f[j] = (short)f2bf(v);
            }
            Bf[ij][kk] = f;
        }
    }

    float accv[4] = {0.f, 0.f, 0.f, 0.f};
    const int tile0 = b * 64 + (w & 1) * 32;   // global A tile index; 32 tiles per wave
    const float* inb = inp + b * 16384;

    uint4 Acur[5], Anxt[5];
    float vcur[4], vnxt[4];
    {
        const int tg = tile0;
#pragma unroll
        for (int kk = 0; kk < 5; ++kk) Acur[kk] = Aw[(tg * 5 + kk) * 64 + l];
        const int pqb = (tg & 63) * 16 + quad * 4;
#pragma unroll
        for (int r = 0; r < 4; ++r) vcur[r] = inb[(pqb + r) * 16 + col];
    }

    for (int i = 0; i < 32; ++i) {
        const int tg = tile0 + i;
        if (i < 31) {
            const int tn = tg + 1;
#pragma unroll
            for (int kk = 0; kk < 5; ++kk) Anxt[kk] = Aw[(tn * 5 + kk) * 64 + l];
            const int pqb = (tn & 63) * 16 + quad * 4;
#pragma unroll
            for (int r = 0; r < 4; ++r) vnxt[r] = inb[(pqb + r) * 16 + col];
        }

        f32x4 C[4];
#pragma unroll
        for (int ij = 0; ij < 4; ++ij) C[ij] = (f32x4){0.f, 0.f, 0.f, 0.f};
#pragma unroll
        for (int kk = 0; kk < 5; ++kk) {
            const bf16x8 a = __builtin_bit_cast(bf16x8, Acur[kk]);
#pragma unroll
            for (int ij = 0; ij < 4; ++ij)
                C[ij] = __builtin_amdgcn_mfma_f32_16x16x32_bf16(a, Bf[ij][kk], C[ij], 0, 0, 0);
        }

        // fused epilogue: acc += M2*x - W2*relu(x - S); rows pqb..pqb+3, col c
        const int pqb = (tg & 63) * 16 + quad * 4;
#pragma unroll
        for (int ij = 0; ij < 4; ++ij) {
            const float4 w2 = *(const float4*)&W2l[ij * 1024 + pqb];
            const float4 m2 = *(const float4*)&M2l[ij * 1024 + pqb];
            accv[ij] += m2.x * vcur[0] - w2.x * fmaxf(vcur[0] - C[ij][0], 0.f);
            accv[ij] += m2.y * vcur[1] - w2.y * fmaxf(vcur[1] - C[ij][1], 0.f);
            accv[ij] += m2.z * vcur[2] - w2.z * fmaxf(vcur[2] - C[ij][2], 0.f);
            accv[ij] += m2.w * vcur[3] - w2.w * fmaxf(vcur[3] - C[ij][3], 0.f);
        }

#pragma unroll
        for (int kk = 0; kk < 5; ++kk) Acur[kk] = Anxt[kk];
#pragma unroll
        for (int r = 0; r < 4; ++r) vcur[r] = vnxt[r];
    }

    // reduce over quads (rows) -> per-wave totals for (ij, col)
#pragma unroll
    for (int ij = 0; ij < 4; ++ij) {
        float v = accv[ij];
        v += __shfl_xor(v, 16);
        v += __shfl_xor(v, 32);
        if (l < 16) red[w][ij * 16 + l] = v;
    }
    __syncthreads();

    if (t < 256) {
        const int ob = t >> 6, oij = (t >> 4) & 3, oc = t & 15;
        const float r0 = red[ob * 2][oij * 16 + oc] + red[ob * 2 + 1][oij * 16 + oc];
        out[ob * 16384 + (bid * 4 + oij) * 16 + oc] = r0;   // L = 1
    }
}

extern "C" void kernel_launch(void* const* d_in, const int* in_sizes, int n_in,
                              void* d_out, int out_size, void* d_ws, size_t ws_size,
                              hipStream_t stream) {
    const float* inp = (const float*)d_in[0];   // 65536
    const float* M   = (const float*)d_in[1];   // 1048576
    const float* Wp  = (const float*)d_in[2];   // 1048576
    const float* G   = (const float*)d_in[3];   // 2359296
    float* out = (float*)d_out;

    uint4* A = (uint4*)d_ws;                    // 4096*160*2B = 1.31 MB
    build_A<<<dim3(16), dim3(256), 0, stream>>>(inp, A);
    inrf_main<<<dim3(256), dim3(512), 0, stream>>>(inp, M, Wp, G, A, out);
}